// Round 1
// baseline (2155.777 us; speedup 1.0000x reference)
//
#include <hip/hip_runtime.h>
#include <math.h>

#define NPTS 50000
#define MN 1024
#define KK 64
#define DPT 64
#define DN 256
#define BCORR 256
#define OUTC 1024
#define OTI 100
#define NEGV (-1e4f)
#define EPSV 1e-8f
#define CAPL 512
#define CCAP 16384

// ---------------- utility ----------------
__global__ void zero_u32_kernel(unsigned* __restrict__ p, int n){
  for (int i=blockIdx.x*blockDim.x+threadIdx.x; i<n; i+=gridDim.x*blockDim.x) p[i]=0u;
}
__global__ void zero_f32_kernel(float* __restrict__ p, int n){
  for (int i=blockIdx.x*blockDim.x+threadIdx.x; i<n; i+=gridDim.x*blockDim.x) p[i]=0.0f;
}

__device__ __forceinline__ float blockReduceSum256(float v, float* red){
  int t=threadIdx.x;
  red[t]=v; __syncthreads();
  #pragma unroll
  for (int s=128;s>0;s>>=1){ if(t<s) red[t]+=red[t+s]; __syncthreads(); }
  float r=red[0]; __syncthreads();
  return r;
}

// node feats: out = l2norm(x @ W^T + b); sq = sum(out^2) (for sq_dist fidelity)
__global__ __launch_bounds__(256) void node_feat_kernel(
    const float* __restrict__ x, const float* __restrict__ W,
    const float* __restrict__ bias, float* __restrict__ out, float* __restrict__ sq){
  __shared__ float xs[DN];
  __shared__ float red[256];
  int m=blockIdx.x, i=threadIdx.x;
  xs[i]=x[m*DN+i];
  __syncthreads();
  float acc=bias[i];
  const float* wr=W+(size_t)i*DN;
  for (int k=0;k<DN;k++) acc=fmaf(wr[k],xs[k],acc);
  float ssq=blockReduceSum256(acc*acc,red);
  float o=acc/sqrtf(ssq);
  out[m*DN+i]=o;
  float s2=blockReduceSum256(o*o,red);
  if(i==0) sq[m]=s2;
}

// nearest node per point (argmin over gram-trick distance, first-min tie rule)
__global__ __launch_bounds__(256) void p2n_kernel(
    const float* __restrict__ pts, const float* __restrict__ nodes, int* __restrict__ p2n){
  __shared__ float nx[MN], ny[MN], nz[MN], nn[MN];
  for (int j=threadIdx.x;j<MN;j+=256){
    float a=nodes[j*3+0], b=nodes[j*3+1], c=nodes[j*3+2];
    nx[j]=a; ny[j]=b; nz[j]=c; nn[j]=a*a+b*b+c*c;
  }
  __syncthreads();
  int id=blockIdx.x*256+threadIdx.x;
  if (id>=NPTS) return;
  float px=pts[id*3+0], py=pts[id*3+1], pz=pts[id*3+2];
  float pp=px*px+py*py+pz*pz;
  float best=3.4e38f; int bi=0;
  for (int j=0;j<MN;j++){
    float d=pp+nn[j]-2.0f*(px*nx[j]+py*ny[j]+pz*nz[j]);
    if (d<best){best=d;bi=j;}
  }
  p2n[id]=bi;
}

__global__ __launch_bounds__(256) void scatter_kernel(
    const int* __restrict__ p2n, int* __restrict__ cnt, int* __restrict__ list){
  int id=blockIdx.x*256+threadIdx.x;
  if (id>=NPTS) return;
  int n=p2n[id];
  int t=atomicAdd(&cnt[n],1);
  if (t<CAPL) list[(size_t)n*CAPL+t]=id;
}

// per-node kNN: sort assigned points by (dist asc, idx asc), keep first 64, pad NPTS
__global__ __launch_bounds__(256) void knn_kernel(
    const float* __restrict__ pts, const float* __restrict__ nodes,
    const int* __restrict__ cnt, const int* __restrict__ list, int* __restrict__ knn){
  __shared__ float ds[CAPL];
  __shared__ int is[CAPL];
  int m=blockIdx.x;
  int c=cnt[m]; if (c>CAPL) c=CAPL;
  float ax=nodes[m*3+0], ay=nodes[m*3+1], az=nodes[m*3+2];
  float nn2=ax*ax+ay*ay+az*az;
  for (int e=threadIdx.x;e<c;e+=256){
    int p=list[(size_t)m*CAPL+e];
    float px=pts[p*3+0],py=pts[p*3+1],pz=pts[p*3+2];
    float pp=px*px+py*py+pz*pz;
    ds[e]=pp+nn2-2.0f*(px*ax+py*ay+pz*az);
    is[e]=p;
  }
  for (int k=threadIdx.x;k<KK;k+=256) knn[m*KK+k]=NPTS;
  __syncthreads();
  for (int e=threadIdx.x;e<c;e+=256){
    float d=ds[e]; int p=is[e]; int r=0;
    for (int j=0;j<c;j++){
      float dj=ds[j];
      r += (dj<d || (dj==d && is[j]<p)) ? 1 : 0;
    }
    if (r<KK) knn[m*KK+r]=p;
  }
}

// coarse scores: exp(-(tt+ss-2*dot)) masked by node validity
__global__ __launch_bounds__(256) void coarse_score_kernel(
    const float* __restrict__ tf, const float* __restrict__ sf,
    const float* __restrict__ tt, const float* __restrict__ ssv,
    const int* __restrict__ cnt_t, const int* __restrict__ cnt_s, float* __restrict__ S){
  __shared__ float ti[DN];
  int i=blockIdx.x;
  for (int k=threadIdx.x;k<DN;k+=256) ti[k]=tf[(size_t)i*DN+k];
  __syncthreads();
  int tv=cnt_t[i]>0;
  float tti=tt[i];
  for (int j=threadIdx.x;j<MN;j+=256){
    const float* sr=sf+(size_t)j*DN;
    float dot=0.0f;
    for (int k=0;k<DN;k++) dot=fmaf(ti[k],sr[k],dot);
    float d=tti+ssv[j]-2.0f*dot;
    float v=expf(-d);
    S[(size_t)i*MN+j]=(tv && cnt_s[j]>0)? v : 0.0f;
  }
}

__global__ __launch_bounds__(256) void rowsum_kernel(const float* __restrict__ S, float* __restrict__ rs){
  __shared__ float red[256];
  int i=blockIdx.x;
  float a=0;
  for (int j=threadIdx.x;j<MN;j+=256) a+=S[(size_t)i*MN+j];
  float r=blockReduceSum256(a,red);
  if (threadIdx.x==0) rs[i]=r;
}
__global__ __launch_bounds__(256) void colsum_kernel(const float* __restrict__ S, float* __restrict__ cs){
  __shared__ float red[256];
  int j=blockIdx.x;
  float a=0;
  for (int i=threadIdx.x;i<MN;i+=256) a+=S[(size_t)i*MN+j];
  float r=blockReduceSum256(a,red);
  if (threadIdx.x==0) cs[j]=r;
}
__global__ __launch_bounds__(256) void dualnorm_kernel(
    float* __restrict__ S, const float* __restrict__ rs, const float* __restrict__ cs){
  int idx=blockIdx.x*256+threadIdx.x;
  int i=idx>>10, j=idx&1023;
  float v=S[idx];
  S[idx]=(v/(rs[i]+EPSV))*(v/(cs[j]+EPSV));
}

// ---------- generic deterministic top-k (value desc, index asc) ----------
__global__ void hist_kernel(const float* __restrict__ arr, int n, unsigned* __restrict__ hist){
  for (int i=blockIdx.x*blockDim.x+threadIdx.x; i<n; i+=gridDim.x*blockDim.x){
    float v=arr[i];
    if (v>0.0f) atomicAdd(&hist[__float_as_uint(v)>>16],1u);
  }
}
__global__ __launch_bounds__(256) void scan_kernel(
    const unsigned* __restrict__ hist, int k, unsigned* __restrict__ meta){
  __shared__ unsigned ls[256];
  int t=threadIdx.x;
  unsigned a=0;
  const unsigned* hp=hist+(size_t)t*256;
  for (int b=0;b<256;b++) a+=hp[b];
  ls[t]=a; __syncthreads();
  if (t==0){
    unsigned cum=0; int T=0; int ch;
    for (ch=255; ch>=0; ch--){
      if (cum+ls[ch] >= (unsigned)k) break;
      cum+=ls[ch];
    }
    if (ch>=0){
      for (int bb=ch*256+255;; bb--){
        cum+=hist[bb];
        if (cum>=(unsigned)k || bb==ch*256){ T=bb; break; }
      }
    }
    meta[0]=(unsigned)T;
    meta[1]=0u;   // candidate counter
  }
}
__global__ void compact_kernel(const float* __restrict__ arr, int n,
                               const unsigned* __restrict__ meta,
                               float* __restrict__ cv, int* __restrict__ ci,
                               unsigned* __restrict__ cnt){
  unsigned T=meta[0];
  for (int i=blockIdx.x*blockDim.x+threadIdx.x; i<n; i+=gridDim.x*blockDim.x){
    float v=arr[i];
    if (v>0.0f && (__float_as_uint(v)>>16)>=T){
      unsigned p=atomicAdd(cnt,1u);
      if (p<CCAP){ cv[p]=v; ci[p]=i; }
    }
  }
}
__global__ __launch_bounds__(256) void rank_coarse_kernel(
    const float* __restrict__ cv, const int* __restrict__ ci, const unsigned* __restrict__ meta,
    int* __restrict__ ti, int* __restrict__ si){
  int c=(int)meta[1]; if (c>CCAP) c=CCAP;
  int t=blockIdx.x*256+threadIdx.x;
  if (t>=c) return;
  float v=cv[t]; int idx=ci[t];
  int rk=0;
  for (int j=0;j<c;j++){
    float vj=cv[j]; int ij=ci[j];
    rk += (vj>v || (vj==v && ij<idx)) ? 1 : 0;
  }
  if (rk<BCORR){ ti[rk]=idx/MN; si[rk]=idx%MN; }
}
__global__ __launch_bounds__(256) void rank_fine_kernel(
    const float* __restrict__ cv, const int* __restrict__ ci, const unsigned* __restrict__ meta,
    const int* __restrict__ sel_t, const int* __restrict__ sel_s,
    const float* __restrict__ tpts, const float* __restrict__ spts,
    float* __restrict__ tp, float* __restrict__ sp, float* __restrict__ cs){
  int c=(int)meta[1]; if (c>CCAP) c=CCAP;
  int t=blockIdx.x*256+threadIdx.x;
  if (t>=c) return;
  float v=cv[t]; int idx=ci[t];
  int rk=0;
  for (int j=0;j<c;j++){
    float vj=cv[j]; int ij=ci[j];
    rk += (vj>v || (vj==v && ij<idx)) ? 1 : 0;
  }
  if (rk<OUTC){
    int b=idx>>12, r=(idx>>6)&63, cc=idx&63;
    int tpi=sel_t[b*KK+r], spi=sel_s[b*KK+cc];
    float tx=0,ty=0,tz=0,sx=0,sy=0,sz=0;
    if (tpi<NPTS){ tx=tpts[tpi*3]; ty=tpts[tpi*3+1]; tz=tpts[tpi*3+2]; }
    if (spi<NPTS){ sx=spts[spi*3]; sy=spts[spi*3+1]; sz=spts[spi*3+2]; }
    tp[rk*3+0]=tx; tp[rk*3+1]=ty; tp[rk*3+2]=tz;
    sp[rk*3+0]=sx; sp[rk*3+1]=sy; sp[rk*3+2]=sz;
    cs[rk]=v;
  }
}

// ---------- patch assembly / OT / fine ----------
__global__ void gather_sel_kernel(const int* __restrict__ ci, const int* __restrict__ knn,
                                  int* __restrict__ sel){
  int b=blockIdx.x, k=threadIdx.x;
  sel[b*KK+k]=knn[ci[b]*KK+k];
}

// selected point features: W(256x64) @ x + b; padded index -> zero vector
__global__ __launch_bounds__(256) void sel_feat_kernel(
    const int* __restrict__ sel, const float* __restrict__ ptf,
    const float* __restrict__ W, const float* __restrict__ bias, float* __restrict__ out){
  __shared__ float xs[DPT];
  int j=blockIdx.x, i=threadIdx.x;
  int p=sel[j];
  if (p==NPTS){ out[(size_t)j*DN+i]=0.0f; return; }   // block-uniform branch
  if (i<DPT) xs[i]=ptf[(size_t)p*DPT+i];
  __syncthreads();
  float acc=bias[i];
  const float* wr=W+(size_t)i*DPT;
  for (int k=0;k<DPT;k++) acc=fmaf(wr[k],xs[k],acc);
  out[(size_t)j*DN+i]=acc;
}

// build padded OT input P (65x65) per batch, with alpha dustbin + NEG masking
__global__ __launch_bounds__(256) void pbuild_kernel(
    const float* __restrict__ ft, const float* __restrict__ fs,
    const int* __restrict__ sel_t, const int* __restrict__ sel_s,
    const float* __restrict__ alpha_p, float* __restrict__ P){
  __shared__ int tm[KK], smk[KK];
  int b=blockIdx.x;
  if (threadIdx.x<KK){
    tm[threadIdx.x]= (sel_t[b*KK+threadIdx.x]!=NPTS);
    smk[threadIdx.x]= (sel_s[b*KK+threadIdx.x]!=NPTS);
  }
  __syncthreads();
  float alpha=alpha_p[0];
  const float* tb=ft+(size_t)b*KK*DN;
  const float* sb=fs+(size_t)b*KK*DN;
  float* Pb=P+(size_t)b*65*65;
  for (int e=threadIdx.x;e<65*65;e+=256){
    int r=e/65, c=e-65*r;
    bool inv=(r<KK && !tm[r]) || (c<KK && !smk[c]);
    float val;
    if (r==KK || c==KK) val=alpha;
    else {
      const float* tr=tb+(size_t)r*DN;
      const float* sr=sb+(size_t)c*DN;
      float dot=0.0f;
      for (int k=0;k<DN;k++) dot=fmaf(tr[k],sr[k],dot);
      val=dot*0.0625f;   // / sqrt(256)
    }
    Pb[e]= inv ? NEGV : val;
  }
}

// Sinkhorn: 100 iters, one block per batch, P in LDS; writes final ms in place
__global__ __launch_bounds__(128) void ot_kernel(
    float* __restrict__ P, const int* __restrict__ sel_t, const int* __restrict__ sel_s){
  __shared__ float Ps[65*65];
  __shared__ float u[65], v[65], lmu[65], lnu[65];
  __shared__ float nrm;
  __shared__ int nrs, ncs;
  int b=blockIdx.x, t=threadIdx.x;
  float* Pg=P+(size_t)b*65*65;
  for (int e=t;e<65*65;e+=128) Ps[e]=Pg[e];
  if (t==0){
    int nr=0,nc=0;
    for (int k=0;k<KK;k++){ nr+=(sel_t[b*KK+k]!=NPTS); nc+=(sel_s[b*KK+k]!=NPTS); }
    nrs=nr; ncs=nc;
    nrm=-logf((float)(nr+nc));
  }
  __syncthreads();
  if (t<65){
    bool rv=(t<KK)? (sel_t[b*KK+t]!=NPTS) : true;
    bool cv=(t<KK)? (sel_s[b*KK+t]!=NPTS) : true;
    float lm=(t==KK)? (logf((float)ncs)+nrm) : nrm;
    float ln=(t==KK)? (logf((float)nrs)+nrm) : nrm;
    lmu[t]= rv? lm : NEGV;
    lnu[t]= cv? ln : NEGV;
    u[t]=0.0f; v[t]=0.0f;
  }
  __syncthreads();
  for (int it=0; it<OTI; it++){
    if (t<65){
      const float* row=Ps+t*65;
      float mx=-3.4e38f;
      for (int c=0;c<65;c++) mx=fmaxf(mx,row[c]+v[c]);
      float sum=0.0f;
      for (int c=0;c<65;c++) sum+=expf(row[c]+v[c]-mx);
      u[t]=lmu[t]-(logf(sum)+mx);
    }
    __syncthreads();
    if (t<65){
      float mx=-3.4e38f;
      for (int r=0;r<65;r++) mx=fmaxf(mx,Ps[r*65+t]+u[r]);
      float sum=0.0f;
      for (int r=0;r<65;r++) sum+=expf(Ps[r*65+t]+u[r]-mx);
      v[t]=lnu[t]-(logf(sum)+mx);
    }
    __syncthreads();
  }
  for (int e=t;e<65*65;e+=128){
    int r=e/65, c=e-65*r;
    Pg[e]=Ps[e]+u[r]+v[c]-nrm;
  }
}

// fine prep: s=exp(ms[:, :64, :64]); mutual top-3 + threshold + masks -> sm
__global__ __launch_bounds__(256) void fineprep_kernel(
    const float* __restrict__ P, const int* __restrict__ sel_t, const int* __restrict__ sel_s,
    float* __restrict__ smout){
  __shared__ float s[KK*KK];
  __shared__ unsigned long long rowm[KK], colm[KK];
  __shared__ int tmk[KK], smk[KK];
  int b=blockIdx.x, t=threadIdx.x;
  const float* Pb=P+(size_t)b*65*65;
  for (int e=t;e<KK*KK;e+=256){
    int r=e>>6, c=e&63;
    s[e]=expf(Pb[r*65+c]);
  }
  if (t<KK){ tmk[t]=(sel_t[b*KK+t]!=NPTS); smk[t]=(sel_s[b*KK+t]!=NPTS); }
  __syncthreads();
  if (t<KK){
    float v1=-1,v2=-1,v3=-1; int i1=0,i2=0,i3=0;
    const float* row=s+t*KK;
    for (int c=0;c<KK;c++){ float v=row[c];
      if (v>v1){v3=v2;i3=i2;v2=v1;i2=i1;v1=v;i1=c;}
      else if (v>v2){v3=v2;i3=i2;v2=v;i2=c;}
      else if (v>v3){v3=v;i3=c;}
    }
    rowm[t]=(1ULL<<i1)|(1ULL<<i2)|(1ULL<<i3);
  } else if (t<2*KK){
    int c=t-KK;
    float v1=-1,v2=-1,v3=-1; int i1=0,i2=0,i3=0;
    for (int r=0;r<KK;r++){ float v=s[r*KK+c];
      if (v>v1){v3=v2;i3=i2;v2=v1;i2=i1;v1=v;i1=r;}
      else if (v>v2){v3=v2;i3=i2;v2=v;i2=r;}
      else if (v>v3){v3=v;i3=r;}
    }
    colm[c]=(1ULL<<i1)|(1ULL<<i2)|(1ULL<<i3);
  }
  __syncthreads();
  for (int e=t;e<KK*KK;e+=256){
    int r=e>>6, c=e&63;
    float v=s[e];
    bool keep = ((rowm[r]>>c)&1ULL) && ((colm[c]>>r)&1ULL) && (v>0.05f) && tmk[r] && smk[c];
    smout[(size_t)b*KK*KK+e]= keep? v : 0.0f;
  }
}

extern "C" void kernel_launch(void* const* d_in, const int* in_sizes, int n_in,
                              void* d_out, int out_size, void* d_ws, size_t ws_size,
                              hipStream_t stream){
  const float* src_pts=(const float*)d_in[0];
  const float* tgt_pts=(const float*)d_in[1];
  const float* src_pf =(const float*)d_in[2];
  const float* tgt_pf =(const float*)d_in[3];
  const float* src_nf =(const float*)d_in[4];
  const float* tgt_nf =(const float*)d_in[5];
  const float* src_nx =(const float*)d_in[6];
  const float* tgt_nx =(const float*)d_in[7];
  const float* cw=(const float*)d_in[8];
  const float* cb=(const float*)d_in[9];
  const float* fw=(const float*)d_in[10];
  const float* fb=(const float*)d_in[11];
  const float* alpha=(const float*)d_in[12];

  char* ws=(char*)d_ws;
  size_t off=0;
  auto A=[&](size_t bytes)->char*{
    char* p=ws+off; off+=(bytes+255)&~(size_t)255; return p; };

  float* tf    =(float*)A((size_t)MN*DN*4);
  float* sfb   =(float*)A((size_t)MN*DN*4);
  float* tt    =(float*)A(MN*4);
  float* ssv   =(float*)A(MN*4);
  int*   p2n_s =(int*)A((size_t)NPTS*4);
  int*   p2n_t =(int*)A((size_t)NPTS*4);
  int*   cnt_s =(int*)A(MN*4);
  int*   cnt_t =(int*)A(MN*4);
  int*   list_s=(int*)A((size_t)MN*CAPL*4);
  int*   list_t=(int*)A((size_t)MN*CAPL*4);
  int*   knn_s =(int*)A((size_t)MN*KK*4);
  int*   knn_t =(int*)A((size_t)MN*KK*4);
  float* Smat  =(float*)A((size_t)MN*MN*4);
  float* rs    =(float*)A(MN*4);
  float* cs    =(float*)A(MN*4);
  unsigned* hist=(unsigned*)A(65536*4);
  unsigned* meta=(unsigned*)A(256);
  float* cand_v=(float*)A((size_t)CCAP*4);
  int*   cand_i=(int*)A((size_t)CCAP*4);
  int*   ci_t  =(int*)A(BCORR*4);
  int*   ci_s  =(int*)A(BCORR*4);
  int*   sel_t =(int*)A((size_t)BCORR*KK*4);
  int*   sel_s =(int*)A((size_t)BCORR*KK*4);
  float* feat_t=(float*)A((size_t)BCORR*KK*DN*4);
  float* feat_s=(float*)A((size_t)BCORR*KK*DN*4);
  float* smf   =(float*)A((size_t)BCORR*KK*KK*4);

  float* out=(float*)d_out;
  float* msout=out;
  float* tpout=out+(size_t)BCORR*65*65;
  float* spout=tpout+(size_t)OUTC*3;
  float* csout=spout+(size_t)OUTC*3;

  const int PB=(NPTS+255)/256;

  node_feat_kernel<<<MN,256,0,stream>>>(tgt_nf,cw,cb,tf,tt);
  node_feat_kernel<<<MN,256,0,stream>>>(src_nf,cw,cb,sfb,ssv);
  p2n_kernel<<<PB,256,0,stream>>>(src_pts,src_nx,p2n_s);
  p2n_kernel<<<PB,256,0,stream>>>(tgt_pts,tgt_nx,p2n_t);
  zero_u32_kernel<<<8,256,0,stream>>>((unsigned*)cnt_s,MN);
  zero_u32_kernel<<<8,256,0,stream>>>((unsigned*)cnt_t,MN);
  scatter_kernel<<<PB,256,0,stream>>>(p2n_s,cnt_s,list_s);
  scatter_kernel<<<PB,256,0,stream>>>(p2n_t,cnt_t,list_t);
  knn_kernel<<<MN,256,0,stream>>>(src_pts,src_nx,cnt_s,list_s,knn_s);
  knn_kernel<<<MN,256,0,stream>>>(tgt_pts,tgt_nx,cnt_t,list_t,knn_t);

  coarse_score_kernel<<<MN,256,0,stream>>>(tf,sfb,tt,ssv,cnt_t,cnt_s,Smat);
  rowsum_kernel<<<MN,256,0,stream>>>(Smat,rs);
  colsum_kernel<<<MN,256,0,stream>>>(Smat,cs);
  dualnorm_kernel<<<4096,256,0,stream>>>(Smat,rs,cs);

  zero_u32_kernel<<<256,256,0,stream>>>(hist,65536);
  hist_kernel<<<2048,256,0,stream>>>(Smat,MN*MN,hist);
  scan_kernel<<<1,256,0,stream>>>(hist,BCORR,meta);
  compact_kernel<<<2048,256,0,stream>>>(Smat,MN*MN,meta,cand_v,cand_i,meta+1);
  zero_u32_kernel<<<1,256,0,stream>>>((unsigned*)ci_t,BCORR);
  zero_u32_kernel<<<1,256,0,stream>>>((unsigned*)ci_s,BCORR);
  rank_coarse_kernel<<<CCAP/256,256,0,stream>>>(cand_v,cand_i,meta,ci_t,ci_s);

  gather_sel_kernel<<<BCORR,KK,0,stream>>>(ci_t,knn_t,sel_t);
  gather_sel_kernel<<<BCORR,KK,0,stream>>>(ci_s,knn_s,sel_s);
  sel_feat_kernel<<<BCORR*KK,256,0,stream>>>(sel_t,tgt_pf,fw,fb,feat_t);
  sel_feat_kernel<<<BCORR*KK,256,0,stream>>>(sel_s,src_pf,fw,fb,feat_s);

  pbuild_kernel<<<BCORR,256,0,stream>>>(feat_t,feat_s,sel_t,sel_s,alpha,msout);
  ot_kernel<<<BCORR,128,0,stream>>>(msout,sel_t,sel_s);

  fineprep_kernel<<<BCORR,256,0,stream>>>(msout,sel_t,sel_s,smf);
  zero_u32_kernel<<<256,256,0,stream>>>(hist,65536);
  hist_kernel<<<2048,256,0,stream>>>(smf,BCORR*KK*KK,hist);
  scan_kernel<<<1,256,0,stream>>>(hist,OUTC,meta);
  compact_kernel<<<2048,256,0,stream>>>(smf,BCORR*KK*KK,meta,cand_v,cand_i,meta+1);
  zero_f32_kernel<<<28,256,0,stream>>>(tpout,OUTC*3*2+OUTC);
  rank_fine_kernel<<<CCAP/256,256,0,stream>>>(cand_v,cand_i,meta,sel_t,sel_s,
                                              tgt_pts,src_pts,tpout,spout,csout);
}

// Round 2
// 1636.470 us; speedup vs baseline: 1.3173x; 1.3173x over previous
//
#include <hip/hip_runtime.h>
#include <math.h>

#define NPTS 50000
#define MN 1024
#define KK 64
#define DPT 64
#define DN 256
#define BCORR 256
#define OUTC 1024
#define OTI 100
#define NEGV (-1e4f)
#define EPSV 1e-8f
#define CAPL 512
#define CCAP 16384
#define HBLK 256   // blocks for histogram passes

// ---------------- utility ----------------
__global__ void zero_u32_kernel(unsigned* __restrict__ p, int n){
  for (int i=blockIdx.x*blockDim.x+threadIdx.x; i<n; i+=gridDim.x*blockDim.x) p[i]=0u;
}
__global__ void zero_f32_kernel(float* __restrict__ p, int n){
  for (int i=blockIdx.x*blockDim.x+threadIdx.x; i<n; i+=gridDim.x*blockDim.x) p[i]=0.0f;
}

__device__ __forceinline__ float blockReduceSum256(float v, float* red){
  int t=threadIdx.x;
  red[t]=v; __syncthreads();
  #pragma unroll
  for (int s=128;s>0;s>>=1){ if(t<s) red[t]+=red[t+s]; __syncthreads(); }
  float r=red[0]; __syncthreads();
  return r;
}

// node feats: out = l2norm(x @ W^T + b); sq = sum(out^2) (for sq_dist fidelity)
__global__ __launch_bounds__(256) void node_feat_kernel(
    const float* __restrict__ x, const float* __restrict__ W,
    const float* __restrict__ bias, float* __restrict__ out, float* __restrict__ sq){
  __shared__ float xs[DN];
  __shared__ float red[256];
  int m=blockIdx.x, i=threadIdx.x;
  xs[i]=x[m*DN+i];
  __syncthreads();
  float acc=bias[i];
  const float* wr=W+(size_t)i*DN;
  for (int k=0;k<DN;k++) acc=fmaf(wr[k],xs[k],acc);
  float ssq=blockReduceSum256(acc*acc,red);
  float o=acc/sqrtf(ssq);
  out[m*DN+i]=o;
  float s2=blockReduceSum256(o*o,red);
  if(i==0) sq[m]=s2;
}

// nearest node per point (argmin over gram-trick distance, first-min tie rule)
__global__ __launch_bounds__(256) void p2n_kernel(
    const float* __restrict__ pts, const float* __restrict__ nodes, int* __restrict__ p2n){
  __shared__ float nx[MN], ny[MN], nz[MN], nn[MN];
  for (int j=threadIdx.x;j<MN;j+=256){
    float a=nodes[j*3+0], b=nodes[j*3+1], c=nodes[j*3+2];
    nx[j]=a; ny[j]=b; nz[j]=c; nn[j]=a*a+b*b+c*c;
  }
  __syncthreads();
  int id=blockIdx.x*256+threadIdx.x;
  if (id>=NPTS) return;
  float px=pts[id*3+0], py=pts[id*3+1], pz=pts[id*3+2];
  float pp=px*px+py*py+pz*pz;
  float best=3.4e38f; int bi=0;
  for (int j=0;j<MN;j++){
    float d=pp+nn[j]-2.0f*(px*nx[j]+py*ny[j]+pz*nz[j]);
    if (d<best){best=d;bi=j;}
  }
  p2n[id]=bi;
}

__global__ __launch_bounds__(256) void scatter_kernel(
    const int* __restrict__ p2n, int* __restrict__ cnt, int* __restrict__ list){
  int id=blockIdx.x*256+threadIdx.x;
  if (id>=NPTS) return;
  int n=p2n[id];
  int t=atomicAdd(&cnt[n],1);
  if (t<CAPL) list[(size_t)n*CAPL+t]=id;
}

// per-node kNN: sort assigned points by (dist asc, idx asc), keep first 64, pad NPTS
__global__ __launch_bounds__(256) void knn_kernel(
    const float* __restrict__ pts, const float* __restrict__ nodes,
    const int* __restrict__ cnt, const int* __restrict__ list, int* __restrict__ knn){
  __shared__ float ds[CAPL];
  __shared__ int is[CAPL];
  int m=blockIdx.x;
  int c=cnt[m]; if (c>CAPL) c=CAPL;
  float ax=nodes[m*3+0], ay=nodes[m*3+1], az=nodes[m*3+2];
  float nn2=ax*ax+ay*ay+az*az;
  for (int e=threadIdx.x;e<c;e+=256){
    int p=list[(size_t)m*CAPL+e];
    float px=pts[p*3+0],py=pts[p*3+1],pz=pts[p*3+2];
    float pp=px*px+py*py+pz*pz;
    ds[e]=pp+nn2-2.0f*(px*ax+py*ay+pz*az);
    is[e]=p;
  }
  for (int k=threadIdx.x;k<KK;k+=256) knn[m*KK+k]=NPTS;
  __syncthreads();
  for (int e=threadIdx.x;e<c;e+=256){
    float d=ds[e]; int p=is[e]; int r=0;
    for (int j=0;j<c;j++){
      float dj=ds[j];
      r += (dj<d || (dj==d && is[j]<p)) ? 1 : 0;
    }
    if (r<KK) knn[m*KK+r]=p;
  }
}

// coarse scores: exp(-(tt+ss-2*dot)) masked by node validity
__global__ __launch_bounds__(256) void coarse_score_kernel(
    const float* __restrict__ tf, const float* __restrict__ sf,
    const float* __restrict__ tt, const float* __restrict__ ssv,
    const int* __restrict__ cnt_t, const int* __restrict__ cnt_s, float* __restrict__ S){
  __shared__ float ti[DN];
  int i=blockIdx.x;
  for (int k=threadIdx.x;k<DN;k+=256) ti[k]=tf[(size_t)i*DN+k];
  __syncthreads();
  int tv=cnt_t[i]>0;
  float tti=tt[i];
  for (int j=threadIdx.x;j<MN;j+=256){
    const float* sr=sf+(size_t)j*DN;
    float dot=0.0f;
    for (int k=0;k<DN;k++) dot=fmaf(ti[k],sr[k],dot);
    float d=tti+ssv[j]-2.0f*dot;
    float v=expf(-d);
    S[(size_t)i*MN+j]=(tv && cnt_s[j]>0)? v : 0.0f;
  }
}

__global__ __launch_bounds__(256) void rowsum_kernel(const float* __restrict__ S, float* __restrict__ rs){
  __shared__ float red[256];
  int i=blockIdx.x;
  float a=0;
  for (int j=threadIdx.x;j<MN;j+=256) a+=S[(size_t)i*MN+j];
  float r=blockReduceSum256(a,red);
  if (threadIdx.x==0) rs[i]=r;
}
__global__ __launch_bounds__(256) void colsum_kernel(const float* __restrict__ S, float* __restrict__ cs){
  __shared__ float red[256];
  int j=blockIdx.x;
  float a=0;
  for (int i=threadIdx.x;i<MN;i+=256) a+=S[(size_t)i*MN+j];
  float r=blockReduceSum256(a,red);
  if (threadIdx.x==0) cs[j]=r;
}
__global__ __launch_bounds__(256) void dualnorm_kernel(
    float* __restrict__ S, const float* __restrict__ rs, const float* __restrict__ cs){
  int idx=blockIdx.x*256+threadIdx.x;
  int i=idx>>10, j=idx&1023;
  float v=S[idx];
  S[idx]=(v/(rs[i]+EPSV))*(v/(cs[j]+EPSV));
}

// ---------- deterministic top-k, contention-free two-level histogram ----------
// meta layout: [0]=T (16-bit bucket threshold), [1]=candidate counter,
//              [2]=coarse bin CB, [3]=count above CB
__global__ __launch_bounds__(256) void hist_coarse_kernel(
    const float* __restrict__ arr, int n, unsigned* __restrict__ partial){
  __shared__ unsigned lh[256];
  lh[threadIdx.x]=0u; __syncthreads();
  for (int i=blockIdx.x*256+threadIdx.x; i<n; i+=gridDim.x*256){
    float v=arr[i];
    if (v>0.0f) atomicAdd(&lh[__float_as_uint(v)>>24],1u);
  }
  __syncthreads();
  partial[blockIdx.x*256+threadIdx.x]=lh[threadIdx.x];
}
__global__ __launch_bounds__(256) void scan_coarse_kernel(
    const unsigned* __restrict__ partial, int nblk, int k, unsigned* __restrict__ meta){
  __shared__ unsigned h[256];
  int t=threadIdx.x;
  unsigned a=0;
  for (int i=0;i<nblk;i++) a+=partial[(size_t)i*256+t];
  h[t]=a; __syncthreads();
  if (t==0){
    unsigned cum=0; int cb=-1; unsigned above=0;
    for (int b=255;b>=0;b--){
      if (cum+h[b] >= (unsigned)k){ cb=b; above=cum; break; }
      cum+=h[b];
    }
    if (cb<0){ cb=0; above=cum-h[0]; }   // fewer than k positives: T will be 0
    meta[2]=(unsigned)cb; meta[3]=above;
  }
}
__global__ __launch_bounds__(256) void hist_fine_kernel(
    const float* __restrict__ arr, int n, const unsigned* __restrict__ meta,
    unsigned* __restrict__ partial){
  __shared__ unsigned lh[256];
  lh[threadIdx.x]=0u; __syncthreads();
  unsigned CB=meta[2];
  for (int i=blockIdx.x*256+threadIdx.x; i<n; i+=gridDim.x*256){
    float v=arr[i];
    unsigned b=__float_as_uint(v);
    if (v>0.0f && (b>>24)==CB) atomicAdd(&lh[(b>>16)&255u],1u);
  }
  __syncthreads();
  partial[blockIdx.x*256+threadIdx.x]=lh[threadIdx.x];
}
__global__ __launch_bounds__(256) void scan_fine_kernel(
    const unsigned* __restrict__ partial, int nblk, int k, unsigned* __restrict__ meta){
  __shared__ unsigned h[256];
  int t=threadIdx.x;
  unsigned a=0;
  for (int i=0;i<nblk;i++) a+=partial[(size_t)i*256+t];
  h[t]=a; __syncthreads();
  if (t==0){
    unsigned CB=meta[2];
    unsigned cum=meta[3]; int sb=0;
    for (int b=255;b>=0;b--){
      if (cum+h[b] >= (unsigned)k){ sb=b; break; }
      cum+=h[b];
    }
    meta[0]=CB*256u+(unsigned)sb;
    meta[1]=0u;   // reset candidate counter for compact
  }
}
__global__ void compact_kernel(const float* __restrict__ arr, int n,
                               const unsigned* __restrict__ meta,
                               float* __restrict__ cv, int* __restrict__ ci,
                               unsigned* __restrict__ cnt){
  unsigned T=meta[0];
  for (int i=blockIdx.x*blockDim.x+threadIdx.x; i<n; i+=gridDim.x*blockDim.x){
    float v=arr[i];
    if (v>0.0f && (__float_as_uint(v)>>16)>=T){
      unsigned p=atomicAdd(cnt,1u);
      if (p<CCAP){ cv[p]=v; ci[p]=i; }
    }
  }
}
__global__ __launch_bounds__(256) void rank_coarse_kernel(
    const float* __restrict__ cv, const int* __restrict__ ci, const unsigned* __restrict__ meta,
    int* __restrict__ ti, int* __restrict__ si){
  int c=(int)meta[1]; if (c>CCAP) c=CCAP;
  int t=blockIdx.x*256+threadIdx.x;
  if (t>=c) return;
  float v=cv[t]; int idx=ci[t];
  int rk=0;
  for (int j=0;j<c;j++){
    float vj=cv[j]; int ij=ci[j];
    rk += (vj>v || (vj==v && ij<idx)) ? 1 : 0;
  }
  if (rk<BCORR){ ti[rk]=idx/MN; si[rk]=idx%MN; }
}
__global__ __launch_bounds__(256) void rank_fine_kernel(
    const float* __restrict__ cv, const int* __restrict__ ci, const unsigned* __restrict__ meta,
    const int* __restrict__ sel_t, const int* __restrict__ sel_s,
    const float* __restrict__ tpts, const float* __restrict__ spts,
    float* __restrict__ tp, float* __restrict__ sp, float* __restrict__ cs){
  int c=(int)meta[1]; if (c>CCAP) c=CCAP;
  int t=blockIdx.x*256+threadIdx.x;
  if (t>=c) return;
  float v=cv[t]; int idx=ci[t];
  int rk=0;
  for (int j=0;j<c;j++){
    float vj=cv[j]; int ij=ci[j];
    rk += (vj>v || (vj==v && ij<idx)) ? 1 : 0;
  }
  if (rk<OUTC){
    int b=idx>>12, r=(idx>>6)&63, cc=idx&63;
    int tpi=sel_t[b*KK+r], spi=sel_s[b*KK+cc];
    float tx=0,ty=0,tz=0,sx=0,sy=0,sz=0;
    if (tpi<NPTS){ tx=tpts[tpi*3]; ty=tpts[tpi*3+1]; tz=tpts[tpi*3+2]; }
    if (spi<NPTS){ sx=spts[spi*3]; sy=spts[spi*3+1]; sz=spts[spi*3+2]; }
    tp[rk*3+0]=tx; tp[rk*3+1]=ty; tp[rk*3+2]=tz;
    sp[rk*3+0]=sx; sp[rk*3+1]=sy; sp[rk*3+2]=sz;
    cs[rk]=v;
  }
}

// ---------- patch assembly / OT / fine ----------
__global__ void gather_sel_kernel(const int* __restrict__ ci, const int* __restrict__ knn,
                                  int* __restrict__ sel){
  int b=blockIdx.x, k=threadIdx.x;
  sel[b*KK+k]=knn[ci[b]*KK+k];
}

// selected point features: W(256x64) @ x + b; padded index -> zero vector
__global__ __launch_bounds__(256) void sel_feat_kernel(
    const int* __restrict__ sel, const float* __restrict__ ptf,
    const float* __restrict__ W, const float* __restrict__ bias, float* __restrict__ out){
  __shared__ float xs[DPT];
  int j=blockIdx.x, i=threadIdx.x;
  int p=sel[j];
  if (p==NPTS){ out[(size_t)j*DN+i]=0.0f; return; }   // block-uniform branch
  if (i<DPT) xs[i]=ptf[(size_t)p*DPT+i];
  __syncthreads();
  float acc=bias[i];
  const float* wr=W+(size_t)i*DPT;
  for (int k=0;k<DPT;k++) acc=fmaf(wr[k],xs[k],acc);
  out[(size_t)j*DN+i]=acc;
}

// build padded OT input P (65x65) per batch, with alpha dustbin + NEG masking
__global__ __launch_bounds__(256) void pbuild_kernel(
    const float* __restrict__ ft, const float* __restrict__ fs,
    const int* __restrict__ sel_t, const int* __restrict__ sel_s,
    const float* __restrict__ alpha_p, float* __restrict__ P){
  __shared__ int tm[KK], smk[KK];
  int b=blockIdx.x;
  if (threadIdx.x<KK){
    tm[threadIdx.x]= (sel_t[b*KK+threadIdx.x]!=NPTS);
    smk[threadIdx.x]= (sel_s[b*KK+threadIdx.x]!=NPTS);
  }
  __syncthreads();
  float alpha=alpha_p[0];
  const float* tb=ft+(size_t)b*KK*DN;
  const float* sb=fs+(size_t)b*KK*DN;
  float* Pb=P+(size_t)b*65*65;
  for (int e=threadIdx.x;e<65*65;e+=256){
    int r=e/65, c=e-65*r;
    bool inv=(r<KK && !tm[r]) || (c<KK && !smk[c]);
    float val;
    if (r==KK || c==KK) val=alpha;
    else {
      const float* tr=tb+(size_t)r*DN;
      const float* sr=sb+(size_t)c*DN;
      float dot=0.0f;
      for (int k=0;k<DN;k++) dot=fmaf(tr[k],sr[k],dot);
      val=dot*0.0625f;   // / sqrt(256)
    }
    Pb[e]= inv ? NEGV : val;
  }
}

// Sinkhorn: 100 iters, one block per batch, P in LDS; writes final ms in place
__global__ __launch_bounds__(128) void ot_kernel(
    float* __restrict__ P, const int* __restrict__ sel_t, const int* __restrict__ sel_s){
  __shared__ float Ps[65*65];
  __shared__ float u[65], v[65], lmu[65], lnu[65];
  __shared__ float nrm;
  __shared__ int nrs, ncs;
  int b=blockIdx.x, t=threadIdx.x;
  float* Pg=P+(size_t)b*65*65;
  for (int e=t;e<65*65;e+=128) Ps[e]=Pg[e];
  if (t==0){
    int nr=0,nc=0;
    for (int k=0;k<KK;k++){ nr+=(sel_t[b*KK+k]!=NPTS); nc+=(sel_s[b*KK+k]!=NPTS); }
    nrs=nr; ncs=nc;
    nrm=-logf((float)(nr+nc));
  }
  __syncthreads();
  if (t<65){
    bool rv=(t<KK)? (sel_t[b*KK+t]!=NPTS) : true;
    bool cv=(t<KK)? (sel_s[b*KK+t]!=NPTS) : true;
    float lm=(t==KK)? (logf((float)ncs)+nrm) : nrm;
    float ln=(t==KK)? (logf((float)nrs)+nrm) : nrm;
    lmu[t]= rv? lm : NEGV;
    lnu[t]= cv? ln : NEGV;
    u[t]=0.0f; v[t]=0.0f;
  }
  __syncthreads();
  for (int it=0; it<OTI; it++){
    if (t<65){
      const float* row=Ps+t*65;
      float mx=-3.4e38f;
      for (int c=0;c<65;c++) mx=fmaxf(mx,row[c]+v[c]);
      float sum=0.0f;
      for (int c=0;c<65;c++) sum+=expf(row[c]+v[c]-mx);
      u[t]=lmu[t]-(logf(sum)+mx);
    }
    __syncthreads();
    if (t<65){
      float mx=-3.4e38f;
      for (int r=0;r<65;r++) mx=fmaxf(mx,Ps[r*65+t]+u[r]);
      float sum=0.0f;
      for (int r=0;r<65;r++) sum+=expf(Ps[r*65+t]+u[r]-mx);
      v[t]=lnu[t]-(logf(sum)+mx);
    }
    __syncthreads();
  }
  for (int e=t;e<65*65;e+=128){
    int r=e/65, c=e-65*r;
    Pg[e]=Ps[e]+u[r]+v[c]-nrm;
  }
}

// fine prep: s=exp(ms[:, :64, :64]); mutual top-3 + threshold + masks -> sm
__global__ __launch_bounds__(256) void fineprep_kernel(
    const float* __restrict__ P, const int* __restrict__ sel_t, const int* __restrict__ sel_s,
    float* __restrict__ smout){
  __shared__ float s[KK*KK];
  __shared__ unsigned long long rowm[KK], colm[KK];
  __shared__ int tmk[KK], smk[KK];
  int b=blockIdx.x, t=threadIdx.x;
  const float* Pb=P+(size_t)b*65*65;
  for (int e=t;e<KK*KK;e+=256){
    int r=e>>6, c=e&63;
    s[e]=expf(Pb[r*65+c]);
  }
  if (t<KK){ tmk[t]=(sel_t[b*KK+t]!=NPTS); smk[t]=(sel_s[b*KK+t]!=NPTS); }
  __syncthreads();
  if (t<KK){
    float v1=-1,v2=-1,v3=-1; int i1=0,i2=0,i3=0;
    const float* row=s+t*KK;
    for (int c=0;c<KK;c++){ float v=row[c];
      if (v>v1){v3=v2;i3=i2;v2=v1;i2=i1;v1=v;i1=c;}
      else if (v>v2){v3=v2;i3=i2;v2=v;i2=c;}
      else if (v>v3){v3=v;i3=c;}
    }
    rowm[t]=(1ULL<<i1)|(1ULL<<i2)|(1ULL<<i3);
  } else if (t<2*KK){
    int c=t-KK;
    float v1=-1,v2=-1,v3=-1; int i1=0,i2=0,i3=0;
    for (int r=0;r<KK;r++){ float v=s[r*KK+c];
      if (v>v1){v3=v2;i3=i2;v2=v1;i2=i1;v1=v;i1=r;}
      else if (v>v2){v3=v2;i3=i2;v2=v;i2=r;}
      else if (v>v3){v3=v;i3=r;}
    }
    colm[c]=(1ULL<<i1)|(1ULL<<i2)|(1ULL<<i3);
  }
  __syncthreads();
  for (int e=t;e<KK*KK;e+=256){
    int r=e>>6, c=e&63;
    float v=s[e];
    bool keep = ((rowm[r]>>c)&1ULL) && ((colm[c]>>r)&1ULL) && (v>0.05f) && tmk[r] && smk[c];
    smout[(size_t)b*KK*KK+e]= keep? v : 0.0f;
  }
}

extern "C" void kernel_launch(void* const* d_in, const int* in_sizes, int n_in,
                              void* d_out, int out_size, void* d_ws, size_t ws_size,
                              hipStream_t stream){
  const float* src_pts=(const float*)d_in[0];
  const float* tgt_pts=(const float*)d_in[1];
  const float* src_pf =(const float*)d_in[2];
  const float* tgt_pf =(const float*)d_in[3];
  const float* src_nf =(const float*)d_in[4];
  const float* tgt_nf =(const float*)d_in[5];
  const float* src_nx =(const float*)d_in[6];
  const float* tgt_nx =(const float*)d_in[7];
  const float* cw=(const float*)d_in[8];
  const float* cb=(const float*)d_in[9];
  const float* fw=(const float*)d_in[10];
  const float* fb=(const float*)d_in[11];
  const float* alpha=(const float*)d_in[12];

  char* ws=(char*)d_ws;
  size_t off=0;
  auto A=[&](size_t bytes)->char*{
    char* p=ws+off; off+=(bytes+255)&~(size_t)255; return p; };

  float* tf    =(float*)A((size_t)MN*DN*4);
  float* sfb   =(float*)A((size_t)MN*DN*4);
  float* tt    =(float*)A(MN*4);
  float* ssv   =(float*)A(MN*4);
  int*   p2n_s =(int*)A((size_t)NPTS*4);
  int*   p2n_t =(int*)A((size_t)NPTS*4);
  int*   cnt_s =(int*)A(MN*4);
  int*   cnt_t =(int*)A(MN*4);
  int*   list_s=(int*)A((size_t)MN*CAPL*4);
  int*   list_t=(int*)A((size_t)MN*CAPL*4);
  int*   knn_s =(int*)A((size_t)MN*KK*4);
  int*   knn_t =(int*)A((size_t)MN*KK*4);
  float* Smat  =(float*)A((size_t)MN*MN*4);
  unsigned* partial=(unsigned*)A((size_t)HBLK*256*4);
  unsigned* meta=(unsigned*)A(256);
  float* cand_v=(float*)A((size_t)CCAP*4);
  int*   cand_i=(int*)A((size_t)CCAP*4);
  int*   ci_t  =(int*)A(BCORR*4);
  int*   ci_s  =(int*)A(BCORR*4);
  int*   sel_t =(int*)A((size_t)BCORR*KK*4);
  int*   sel_s =(int*)A((size_t)BCORR*KK*4);
  float* feat_t=(float*)A((size_t)BCORR*KK*DN*4);
  float* feat_s=(float*)A((size_t)BCORR*KK*DN*4);
  float* smf   =(float*)A((size_t)BCORR*KK*KK*4);
  float* rs    =(float*)A(MN*4);
  float* csum  =(float*)A(MN*4);

  float* out=(float*)d_out;
  float* msout=out;
  float* tpout=out+(size_t)BCORR*65*65;
  float* spout=tpout+(size_t)OUTC*3;
  float* csout=spout+(size_t)OUTC*3;

  const int PB=(NPTS+255)/256;

  node_feat_kernel<<<MN,256,0,stream>>>(tgt_nf,cw,cb,tf,tt);
  node_feat_kernel<<<MN,256,0,stream>>>(src_nf,cw,cb,sfb,ssv);
  p2n_kernel<<<PB,256,0,stream>>>(src_pts,src_nx,p2n_s);
  p2n_kernel<<<PB,256,0,stream>>>(tgt_pts,tgt_nx,p2n_t);
  zero_u32_kernel<<<8,256,0,stream>>>((unsigned*)cnt_s,MN);
  zero_u32_kernel<<<8,256,0,stream>>>((unsigned*)cnt_t,MN);
  scatter_kernel<<<PB,256,0,stream>>>(p2n_s,cnt_s,list_s);
  scatter_kernel<<<PB,256,0,stream>>>(p2n_t,cnt_t,list_t);
  knn_kernel<<<MN,256,0,stream>>>(src_pts,src_nx,cnt_s,list_s,knn_s);
  knn_kernel<<<MN,256,0,stream>>>(tgt_pts,tgt_nx,cnt_t,list_t,knn_t);

  coarse_score_kernel<<<MN,256,0,stream>>>(tf,sfb,tt,ssv,cnt_t,cnt_s,Smat);
  rowsum_kernel<<<MN,256,0,stream>>>(Smat,rs);
  colsum_kernel<<<MN,256,0,stream>>>(Smat,csum);
  dualnorm_kernel<<<4096,256,0,stream>>>(Smat,rs,csum);

  hist_coarse_kernel<<<HBLK,256,0,stream>>>(Smat,MN*MN,partial);
  scan_coarse_kernel<<<1,256,0,stream>>>(partial,HBLK,BCORR,meta);
  hist_fine_kernel<<<HBLK,256,0,stream>>>(Smat,MN*MN,meta,partial);
  scan_fine_kernel<<<1,256,0,stream>>>(partial,HBLK,BCORR,meta);
  compact_kernel<<<2048,256,0,stream>>>(Smat,MN*MN,meta,cand_v,cand_i,meta+1);
  zero_u32_kernel<<<1,256,0,stream>>>((unsigned*)ci_t,BCORR);
  zero_u32_kernel<<<1,256,0,stream>>>((unsigned*)ci_s,BCORR);
  rank_coarse_kernel<<<CCAP/256,256,0,stream>>>(cand_v,cand_i,meta,ci_t,ci_s);

  gather_sel_kernel<<<BCORR,KK,0,stream>>>(ci_t,knn_t,sel_t);
  gather_sel_kernel<<<BCORR,KK,0,stream>>>(ci_s,knn_s,sel_s);
  sel_feat_kernel<<<BCORR*KK,256,0,stream>>>(sel_t,tgt_pf,fw,fb,feat_t);
  sel_feat_kernel<<<BCORR*KK,256,0,stream>>>(sel_s,src_pf,fw,fb,feat_s);

  pbuild_kernel<<<BCORR,256,0,stream>>>(feat_t,feat_s,sel_t,sel_s,alpha,msout);
  ot_kernel<<<BCORR,128,0,stream>>>(msout,sel_t,sel_s);

  fineprep_kernel<<<BCORR,256,0,stream>>>(msout,sel_t,sel_s,smf);
  hist_coarse_kernel<<<HBLK,256,0,stream>>>(smf,BCORR*KK*KK,partial);
  scan_coarse_kernel<<<1,256,0,stream>>>(partial,HBLK,OUTC,meta);
  hist_fine_kernel<<<HBLK,256,0,stream>>>(smf,BCORR*KK*KK,meta,partial);
  scan_fine_kernel<<<1,256,0,stream>>>(partial,HBLK,OUTC,meta);
  compact_kernel<<<2048,256,0,stream>>>(smf,BCORR*KK*KK,meta,cand_v,cand_i,meta+1);
  zero_f32_kernel<<<28,256,0,stream>>>(tpout,OUTC*3*2+OUTC);
  rank_fine_kernel<<<CCAP/256,256,0,stream>>>(cand_v,cand_i,meta,sel_t,sel_s,
                                              tgt_pts,src_pts,tpout,spout,csout);
}